// Round 13
// baseline (148.752 us; speedup 1.0000x reference)
//
#include <hip/hip_runtime.h>
#include <hip/hip_bf16.h>
#include <cstdint>

#define NV 64000      // B*N nodes
#define DD 64         // hidden dim
#define FF 3          // input features
#define NE 1000000    // edges
#define BB 32         // batch (graphs)
#define SS 50         // timesteps
#define NN 2000       // nodes per graph
#define KB 1000       // coarse buckets (dst >> 6), 64 dsts each
#define CAP 1536      // records per bucket region (mean 1000, +17 sigma)
#define NBLKA 250     // partition blocks
#define EPB (NE / NBLKA)  // 4000 edges per partition block
#define INVALID 0xFFFFFFFFu
#define RPW 16        // rows per wave in trans2pool (2000 % 16 == 0 -> graph-aligned)
#define NWAVES (NV / RPW)   // 4000
#define WPG (NN / RPW)      // 125 partials per graph

// ---------------------------------------------------------------------------
// Fused setup: zero gcur + int64-vs-int32 detection.
// ---------------------------------------------------------------------------
__global__ __launch_bounds__(256) void setup_kernel(const int* __restrict__ ei,
                                                    int* __restrict__ flag,
                                                    int* __restrict__ gcur) {
    int i = blockIdx.x * 256 + threadIdx.x;
    if (i < KB) gcur[i] = 0;
    if (blockIdx.x == 0) {
        __shared__ int nz;
        if (threadIdx.x == 0) nz = 0;
        __syncthreads();
        int local = 0;
        for (int k = threadIdx.x; k < 4096; k += 256)
            local |= (ei[2 * k + 1] != 0);
        if (local) atomicOr(&nz, 1);
        __syncthreads();
        if (threadIdx.x == 0) *flag = (nz == 0) ? 1 : 0;
    }
}

// ---------------------------------------------------------------------------
// Partition edges into KB coarse bucket regions as packed 4B records
// (src<<6)|(dst&63). Single edge-list read; records staged in LDS.
// ---------------------------------------------------------------------------
__global__ __launch_bounds__(256) void part_kernel(const int* __restrict__ ei32,
                                                   const int* __restrict__ flag,
                                                   int* __restrict__ gcur,
                                                   unsigned* __restrict__ parts) {
    __shared__ unsigned recs[EPB];   // 16 KB
    __shared__ int cnt[KB];          // 4 KB
    __shared__ int cur[KB];          // 4 KB
    const long long* ei64 = (const long long*)ei32;
    const int is64 = *flag;
    int t = threadIdx.x;
    int e0 = blockIdx.x * EPB;
    for (int i = t; i < KB; i += 256) cnt[i] = 0;
    __syncthreads();
    for (int i = t; i < EPB; i += 256) {
        int e = e0 + i;
        int s, d;
        if (is64) { s = (int)ei64[e]; d = (int)ei64[NE + e]; }
        else      { s = ei32[e];      d = ei32[NE + e]; }
        bool ok = (unsigned)s < NV && (unsigned)d < NV;
        recs[i] = ok ? (((unsigned)s << 16) | (unsigned)d) : INVALID;
        if (ok) atomicAdd(&cnt[d >> 6], 1);
    }
    __syncthreads();
    for (int b = t; b < KB; b += 256) {
        int c = cnt[b];
        cur[b] = (c > 0) ? atomicAdd(&gcur[b], c) : 0;
    }
    __syncthreads();
    for (int i = t; i < EPB; i += 256) {
        unsigned r = recs[i];
        if (r != INVALID) {
            int d = (int)(r & 0xFFFFu);
            int b = d >> 6;
            int pos = atomicAdd(&cur[b], 1);
            if (pos < CAP)
                parts[(size_t)b * CAP + pos] = ((r >> 16) << 6) | (unsigned)(d & 63);
        }
    }
}

// ---------------------------------------------------------------------------
// Per-bucket LDS counting sort -> beg/end + dinv; sorted src ids in place.
// ---------------------------------------------------------------------------
__global__ __launch_bounds__(256) void bsort_kernel(unsigned* __restrict__ parts,
                                                    const int* __restrict__ gcur,
                                                    int* __restrict__ beg,
                                                    int* __restrict__ end,
                                                    float* __restrict__ dinv) {
    __shared__ unsigned recs[CAP];
    __shared__ int srt[CAP];
    __shared__ int cnt64[64];
    __shared__ int pref[64];
    __shared__ int cur[64];
    int b = blockIdx.x, t = threadIdx.x;
    int cnt = min(gcur[b], CAP);
    unsigned* p = parts + (size_t)b * CAP;
    if (t < 64) cnt64[t] = 0;
    __syncthreads();
    for (int i = t; i < cnt; i += 256) {
        unsigned r = p[i];
        recs[i] = r;
        atomicAdd(&cnt64[r & 63u], 1);
    }
    __syncthreads();
    if (t < 64) pref[t] = cnt64[t];
    __syncthreads();
    #pragma unroll
    for (int off = 1; off < 64; off <<= 1) {
        int v = (t < 64 && t >= off) ? pref[t - off] : 0;
        __syncthreads();
        if (t < 64) pref[t] += v;
        __syncthreads();
    }
    if (t < 64) {
        int ex = pref[t] - cnt64[t];
        cur[t] = ex;
        int node = (b << 6) + t;
        beg[node] = b * CAP + ex;
        end[node] = b * CAP + ex + cnt64[t];
        dinv[node] = rsqrtf((float)(cnt64[t] + 1));
    }
    __syncthreads();
    for (int i = t; i < cnt; i += 256) {
        unsigned r = recs[i];
        int pos = atomicAdd(&cur[r & 63u], 1);
        srt[pos] = (int)(r >> 6);
    }
    __syncthreads();
    for (int i = t; i < cnt; i += 256) p[i] = (unsigned)srt[i];
}

// p0[node*3+f] = dinv[node] * mean over S of x[b][s][n][f]
__global__ void tmean_kernel(const float* __restrict__ x, const float* __restrict__ dinv,
                             float* __restrict__ p0) {
    int tid = blockIdx.x * blockDim.x + threadIdx.x;
    if (tid >= NV * FF) return;
    int nf = tid % (NN * FF);
    int b  = tid / (NN * FF);
    const float* xp = x + (size_t)b * SS * NN * FF + nf;
    float acc = 0.f;
    #pragma unroll
    for (int s = 0; s < SS; ++s) acc += xp[(size_t)s * NN * FF];
    int node = tid / 3;
    p0[tid] = dinv[node] * acc * (1.0f / SS);
}

// 3-dim aggregation: q04 = {sum p0[src] + p0[dst], dinv}. p0 L2-resident.
__global__ __launch_bounds__(256) void agg3_kernel(const int* __restrict__ beg,
                                                   const int* __restrict__ end,
                                                   const unsigned* __restrict__ srcs,
                                                   const float* __restrict__ p0,
                                                   const float* __restrict__ dinv,
                                                   float4* __restrict__ q04) {
    int node = blockIdx.x * 256 + threadIdx.x;
    if (node >= NV) return;
    int e = beg[node], en = end[node];
    float a0 = p0[node * 3 + 0], a1 = p0[node * 3 + 1], a2 = p0[node * 3 + 2];
    for (; e + 2 <= en; e += 2) {
        int s0 = srcs[e] * 3, s1 = srcs[e + 1] * 3;
        float u0 = p0[s0], u1 = p0[s0 + 1], u2 = p0[s0 + 2];
        float w0 = p0[s1], w1 = p0[s1 + 1], w2 = p0[s1 + 2];
        a0 += u0 + w0; a1 += u1 + w1; a2 += u2 + w2;
    }
    for (; e < en; ++e) {
        int s = srcs[e] * 3;
        a0 += p0[s]; a1 += p0[s + 1]; a2 += p0[s + 2];
    }
    q04[node] = make_float4(a0, a1, a2, dinv[node]);
}

// p1 = dinv * relu(dinv*(q0@W1) + b1)
__global__ void trans1_kernel(const float4* __restrict__ q04,
                              const float* __restrict__ W1, const float* __restrict__ b1,
                              float* __restrict__ p1) {
    int tid = blockIdx.x * blockDim.x + threadIdx.x;  // NV*DD
    if (tid >= NV * DD) return;
    int node = tid >> 6, d = tid & 63;
    float4 q = q04[node];
    float h = fmaf(q.w, fmaf(q.x, W1[d], fmaf(q.y, W1[64 + d], q.z * W1[128 + d])), b1[d]);
    p1[tid] = q.w * fmaxf(h, 0.f);
}

// ---------------------------------------------------------------------------
// 64-dim aggregation, float4-per-lane: one wave per dst node; 16-lane group
// g handles edges e0+g, e0+g+4, ...; lane sub gathers one dwordx4 (4 edges
// per vmem instruction). Butterfly (^16,^32) combines; group 0 stores.
// ---------------------------------------------------------------------------
__global__ __launch_bounds__(256) void agg64_kernel(const int* __restrict__ beg,
                                                    const int* __restrict__ end,
                                                    const unsigned* __restrict__ srcs,
                                                    const float* __restrict__ g,
                                                    float* __restrict__ raw) {
    int lane = threadIdx.x & 63;
    int node = (blockIdx.x * blockDim.x + threadIdx.x) >> 6;
    if (node >= NV) return;
    int grp = lane >> 4, sub = lane & 15;
    int e0 = beg[node], en = end[node];
    float4 acc;
    if (grp == 0) {
        acc = ((const float4*)(g + ((size_t)node << 6)))[sub];  // self loop
    } else {
        acc = make_float4(0.f, 0.f, 0.f, 0.f);
    }
    int e = e0 + grp;
    for (; e + 4 < en; e += 8) {
        int s0 = srcs[e], s1 = srcs[e + 4];
        float4 v0 = ((const float4*)(g + ((size_t)s0 << 6)))[sub];
        float4 v1 = ((const float4*)(g + ((size_t)s1 << 6)))[sub];
        acc.x += v0.x + v1.x; acc.y += v0.y + v1.y;
        acc.z += v0.z + v1.z; acc.w += v0.w + v1.w;
    }
    if (e < en) {
        int s = srcs[e];
        float4 v = ((const float4*)(g + ((size_t)s << 6)))[sub];
        acc.x += v.x; acc.y += v.y; acc.z += v.z; acc.w += v.w;
    }
    acc.x += __shfl_xor(acc.x, 16); acc.y += __shfl_xor(acc.y, 16);
    acc.z += __shfl_xor(acc.z, 16); acc.w += __shfl_xor(acc.w, 16);
    acc.x += __shfl_xor(acc.x, 32); acc.y += __shfl_xor(acc.y, 32);
    acc.z += __shfl_xor(acc.z, 32); acc.w += __shfl_xor(acc.w, 32);
    if (grp == 0)
        ((float4*)(raw + ((size_t)node << 6)))[sub] = acc;
}

// ---------------------------------------------------------------------------
// Fused layer-2 transform + partial pooling, v3. W2 staged once per block in
// LDS as w2s[k*64+d] (lane reads column d: bank = d%32, 2-way alias = free).
// Each wave owns RPW=16 rows, processed in chunks of 4: per k, ONE ds_read_b32
// feeds FOUR FMAs (one per row) -> VALU-bound, ~35 VGPRs, no spill possible
// (rounds 10-12 post-mortem: compiler pins this kernel at 64 VGPRs and spills
// any register-resident W2 scheme). q-row reads are wave-uniform float4 loads.
// ---------------------------------------------------------------------------
__global__ __launch_bounds__(256) void trans2pool_kernel(const float* __restrict__ q1,
                                                         const float* __restrict__ dinv,
                                                         const float* __restrict__ b2,
                                                         const float* __restrict__ W2,
                                                         float* __restrict__ partials) {
    __shared__ float w2s[64 * 64];   // 16 KB
    int t = threadIdx.x;
    for (int i = t; i < 64 * 64; i += 256) w2s[i] = W2[i];
    __syncthreads();
    int lane = t & 63;
    int wid = blockIdx.x * 4 + (t >> 6);
    float bb = b2[lane];
    int n0 = wid * RPW;
    float psum = 0.f;
    for (int c = 0; c < RPW; c += 4) {
        int n = n0 + c;
        const float4* q0 = (const float4*)(q1 + ((size_t)(n + 0) << 6));
        const float4* q1p = (const float4*)(q1 + ((size_t)(n + 1) << 6));
        const float4* q2p = (const float4*)(q1 + ((size_t)(n + 2) << 6));
        const float4* q3p = (const float4*)(q1 + ((size_t)(n + 3) << 6));
        float d0 = dinv[n], d1 = dinv[n + 1], d2 = dinv[n + 2], d3 = dinv[n + 3];
        float a0 = 0.f, a1 = 0.f, a2 = 0.f, a3 = 0.f;
        #pragma unroll
        for (int j = 0; j < 16; ++j) {
            float4 v0 = q0[j], v1 = q1p[j], v2 = q2p[j], v3 = q3p[j];
            #pragma unroll
            for (int m = 0; m < 4; ++m) {
                float w = w2s[(4 * j + m) * 64 + lane];
                a0 = fmaf((&v0.x)[m], w, a0);
                a1 = fmaf((&v1.x)[m], w, a1);
                a2 = fmaf((&v2.x)[m], w, a2);
                a3 = fmaf((&v3.x)[m], w, a3);
            }
        }
        psum += fmaxf(fmaf(d0, a0, bb), 0.f);
        psum += fmaxf(fmaf(d1, a1, bb), 0.f);
        psum += fmaxf(fmaf(d2, a2, bb), 0.f);
        psum += fmaxf(fmaf(d3, a3, bb), 0.f);
    }
    partials[(size_t)wid * 64 + lane] = psum;
}

// Reduce WPG=125 partials per graph; apply head.
__global__ __launch_bounds__(64) void pool_finish_kernel(const float* __restrict__ partials,
                                                         const float* __restrict__ Wh,
                                                         const float* __restrict__ bh,
                                                         float* __restrict__ out) {
    __shared__ float pooled[64];
    int b = blockIdx.x;
    int t = threadIdx.x;
    float s = 0.f;
    for (int c = 0; c < WPG; ++c)
        s += partials[((size_t)(b * WPG + c)) * 64 + t];
    pooled[t] = s * (1.0f / NN);
    __syncthreads();
    if (t < 2) {
        float o = bh[t];
        #pragma unroll 16
        for (int k = 0; k < 64; ++k) o += pooled[k] * Wh[k * 2 + t];
        out[b * 2 + t] = o;
    }
}

extern "C" void kernel_launch(void* const* d_in, const int* in_sizes, int n_in,
                              void* d_out, int out_size, void* d_ws, size_t ws_size,
                              hipStream_t stream) {
    const float* x  = (const float*)d_in[0];
    const int*   ei = (const int*)d_in[1];
    const float* W1 = (const float*)d_in[2];
    const float* b1 = (const float*)d_in[3];
    const float* W2 = (const float*)d_in[4];
    const float* b2 = (const float*)d_in[5];
    const float* Wh = (const float*)d_in[6];
    const float* bh = (const float*)d_in[7];
    float* out = (float*)d_out;

    float* ws   = (float*)d_ws;
    float* bufA = ws;                          // NV*DD  (p1)
    float* bufB = bufA + (size_t)NV * DD;      // NV*DD  (q1)
    float* p0   = bufB + (size_t)NV * DD;      // NV*FF
    float4* q04 = (float4*)(p0 + (size_t)NV * FF);  // NV
    float* dinv = (float*)(q04 + NV);          // NV
    float* partials = dinv + NV;               // NWAVES*64
    unsigned* parts = (unsigned*)(partials + (size_t)NWAVES * 64);  // KB*CAP
    int*   beg  = (int*)(parts + (size_t)KB * CAP);                 // NV
    int*   end  = beg + NV;                    // NV
    int*   gcur = end + NV;                    // KB
    int*   flag = gcur + KB;                   // 1

    // --- Build bucketed, per-bucket-sorted edge structure ---
    setup_kernel<<<4, 256, 0, stream>>>(ei, flag, gcur);
    part_kernel<<<NBLKA, 256, 0, stream>>>(ei, flag, gcur, parts);
    bsort_kernel<<<KB, 256, 0, stream>>>(parts, gcur, beg, end, dinv);

    // --- p0 = dinv * temporal-mean(x) ---
    tmean_kernel<<<(NV * FF + 255) / 256, 256, 0, stream>>>(x, dinv, p0);

    // --- Layer 1 aggregation (3-dim gather) -> q04 = {q0, dinv} ---
    agg3_kernel<<<(NV + 255) / 256, 256, 0, stream>>>(beg, end, parts, p0, dinv, q04);

    // --- Layer 1 transform (once per node) ---
    trans1_kernel<<<NV * DD / 256, 256, 0, stream>>>(q04, W1, b1, bufA);

    // --- Layer 2 aggregation (float4-per-lane, 4 edges/instr) ---
    agg64_kernel<<<NV * 64 / 256, 256, 0, stream>>>(beg, end, parts, bufA, bufB);

    // --- Fused layer-2 transform + partial pool (W2 in LDS, 4-row reuse) ---
    trans2pool_kernel<<<NWAVES / 4, 256, 0, stream>>>(bufB, dinv, b2, W2, partials);

    // --- Head ---
    pool_finish_kernel<<<BB, 64, 0, stream>>>(partials, Wh, bh, out);
}

// Round 14
// 119.028 us; speedup vs baseline: 1.2497x; 1.2497x over previous
//
#include <hip/hip_runtime.h>
#include <hip/hip_bf16.h>
#include <cstdint>

#define NV 64000      // B*N nodes
#define DD 64         // hidden dim
#define FF 3          // input features
#define NE 1000000    // edges
#define BB 32         // batch (graphs)
#define SS 50         // timesteps
#define NN 2000       // nodes per graph
#define KB 1000       // coarse buckets (dst >> 6), 64 dsts each
#define CAP 1536      // records per bucket region (mean 1000, +17 sigma)
#define NBLKA 250     // partition blocks
#define EPB (NE / NBLKA)  // 4000 edges per partition block
#define INVALID 0xFFFFFFFFu
#define RPW 16        // rows per wave in trans2pool (2000 % 16 == 0 -> graph-aligned)
#define NWAVES (NV / RPW)   // 4000
#define WPG (NN / RPW)      // 125 partials per graph
#define RST 20        // rT row stride (words): %4==0 keeps b128 alignment

// ---------------------------------------------------------------------------
// Fused setup: zero gcur + int64-vs-int32 detection.
// ---------------------------------------------------------------------------
__global__ __launch_bounds__(256) void setup_kernel(const int* __restrict__ ei,
                                                    int* __restrict__ flag,
                                                    int* __restrict__ gcur) {
    int i = blockIdx.x * 256 + threadIdx.x;
    if (i < KB) gcur[i] = 0;
    if (blockIdx.x == 0) {
        __shared__ int nz;
        if (threadIdx.x == 0) nz = 0;
        __syncthreads();
        int local = 0;
        for (int k = threadIdx.x; k < 4096; k += 256)
            local |= (ei[2 * k + 1] != 0);
        if (local) atomicOr(&nz, 1);
        __syncthreads();
        if (threadIdx.x == 0) *flag = (nz == 0) ? 1 : 0;
    }
}

// ---------------------------------------------------------------------------
// Partition edges into KB coarse bucket regions as packed 4B records
// (src<<6)|(dst&63). Single edge-list read; records staged in LDS.
// ---------------------------------------------------------------------------
__global__ __launch_bounds__(256) void part_kernel(const int* __restrict__ ei32,
                                                   const int* __restrict__ flag,
                                                   int* __restrict__ gcur,
                                                   unsigned* __restrict__ parts) {
    __shared__ unsigned recs[EPB];   // 16 KB
    __shared__ int cnt[KB];          // 4 KB
    __shared__ int cur[KB];          // 4 KB
    const long long* ei64 = (const long long*)ei32;
    const int is64 = *flag;
    int t = threadIdx.x;
    int e0 = blockIdx.x * EPB;
    for (int i = t; i < KB; i += 256) cnt[i] = 0;
    __syncthreads();
    for (int i = t; i < EPB; i += 256) {
        int e = e0 + i;
        int s, d;
        if (is64) { s = (int)ei64[e]; d = (int)ei64[NE + e]; }
        else      { s = ei32[e];      d = ei32[NE + e]; }
        bool ok = (unsigned)s < NV && (unsigned)d < NV;
        recs[i] = ok ? (((unsigned)s << 16) | (unsigned)d) : INVALID;
        if (ok) atomicAdd(&cnt[d >> 6], 1);
    }
    __syncthreads();
    for (int b = t; b < KB; b += 256) {
        int c = cnt[b];
        cur[b] = (c > 0) ? atomicAdd(&gcur[b], c) : 0;
    }
    __syncthreads();
    for (int i = t; i < EPB; i += 256) {
        unsigned r = recs[i];
        if (r != INVALID) {
            int d = (int)(r & 0xFFFFu);
            int b = d >> 6;
            int pos = atomicAdd(&cur[b], 1);
            if (pos < CAP)
                parts[(size_t)b * CAP + pos] = ((r >> 16) << 6) | (unsigned)(d & 63);
        }
    }
}

// ---------------------------------------------------------------------------
// Per-bucket LDS counting sort -> beg/end + dinv; sorted src ids in place.
// ---------------------------------------------------------------------------
__global__ __launch_bounds__(256) void bsort_kernel(unsigned* __restrict__ parts,
                                                    const int* __restrict__ gcur,
                                                    int* __restrict__ beg,
                                                    int* __restrict__ end,
                                                    float* __restrict__ dinv) {
    __shared__ unsigned recs[CAP];
    __shared__ int srt[CAP];
    __shared__ int cnt64[64];
    __shared__ int pref[64];
    __shared__ int cur[64];
    int b = blockIdx.x, t = threadIdx.x;
    int cnt = min(gcur[b], CAP);
    unsigned* p = parts + (size_t)b * CAP;
    if (t < 64) cnt64[t] = 0;
    __syncthreads();
    for (int i = t; i < cnt; i += 256) {
        unsigned r = p[i];
        recs[i] = r;
        atomicAdd(&cnt64[r & 63u], 1);
    }
    __syncthreads();
    if (t < 64) pref[t] = cnt64[t];
    __syncthreads();
    #pragma unroll
    for (int off = 1; off < 64; off <<= 1) {
        int v = (t < 64 && t >= off) ? pref[t - off] : 0;
        __syncthreads();
        if (t < 64) pref[t] += v;
        __syncthreads();
    }
    if (t < 64) {
        int ex = pref[t] - cnt64[t];
        cur[t] = ex;
        int node = (b << 6) + t;
        beg[node] = b * CAP + ex;
        end[node] = b * CAP + ex + cnt64[t];
        dinv[node] = rsqrtf((float)(cnt64[t] + 1));
    }
    __syncthreads();
    for (int i = t; i < cnt; i += 256) {
        unsigned r = recs[i];
        int pos = atomicAdd(&cur[r & 63u], 1);
        srt[pos] = (int)(r >> 6);
    }
    __syncthreads();
    for (int i = t; i < cnt; i += 256) p[i] = (unsigned)srt[i];
}

// p0[node*3+f] = dinv[node] * mean over S of x[b][s][n][f]
__global__ void tmean_kernel(const float* __restrict__ x, const float* __restrict__ dinv,
                             float* __restrict__ p0) {
    int tid = blockIdx.x * blockDim.x + threadIdx.x;
    if (tid >= NV * FF) return;
    int nf = tid % (NN * FF);
    int b  = tid / (NN * FF);
    const float* xp = x + (size_t)b * SS * NN * FF + nf;
    float acc = 0.f;
    #pragma unroll
    for (int s = 0; s < SS; ++s) acc += xp[(size_t)s * NN * FF];
    int node = tid / 3;
    p0[tid] = dinv[node] * acc * (1.0f / SS);
}

// 3-dim aggregation: q04 = {sum p0[src] + p0[dst], dinv}. p0 L2-resident.
__global__ __launch_bounds__(256) void agg3_kernel(const int* __restrict__ beg,
                                                   const int* __restrict__ end,
                                                   const unsigned* __restrict__ srcs,
                                                   const float* __restrict__ p0,
                                                   const float* __restrict__ dinv,
                                                   float4* __restrict__ q04) {
    int node = blockIdx.x * 256 + threadIdx.x;
    if (node >= NV) return;
    int e = beg[node], en = end[node];
    float a0 = p0[node * 3 + 0], a1 = p0[node * 3 + 1], a2 = p0[node * 3 + 2];
    for (; e + 2 <= en; e += 2) {
        int s0 = srcs[e] * 3, s1 = srcs[e + 1] * 3;
        float u0 = p0[s0], u1 = p0[s0 + 1], u2 = p0[s0 + 2];
        float w0 = p0[s1], w1 = p0[s1 + 1], w2 = p0[s1 + 2];
        a0 += u0 + w0; a1 += u1 + w1; a2 += u2 + w2;
    }
    for (; e < en; ++e) {
        int s = srcs[e] * 3;
        a0 += p0[s]; a1 += p0[s + 1]; a2 += p0[s + 2];
    }
    q04[node] = make_float4(a0, a1, a2, dinv[node]);
}

// p1 = dinv * relu(dinv*(q0@W1) + b1)
__global__ void trans1_kernel(const float4* __restrict__ q04,
                              const float* __restrict__ W1, const float* __restrict__ b1,
                              float* __restrict__ p1) {
    int tid = blockIdx.x * blockDim.x + threadIdx.x;  // NV*DD
    if (tid >= NV * DD) return;
    int node = tid >> 6, d = tid & 63;
    float4 q = q04[node];
    float h = fmaf(q.w, fmaf(q.x, W1[d], fmaf(q.y, W1[64 + d], q.z * W1[128 + d])), b1[d]);
    p1[tid] = q.w * fmaxf(h, 0.f);
}

// ---------------------------------------------------------------------------
// 64-dim aggregation, float4-per-lane: one wave per dst node; 16-lane group
// g handles edges e0+g, e0+g+4, ...; lane sub gathers one dwordx4 (4 edges
// per vmem instruction). Butterfly (^16,^32) combines; group 0 stores.
// ---------------------------------------------------------------------------
__global__ __launch_bounds__(256) void agg64_kernel(const int* __restrict__ beg,
                                                    const int* __restrict__ end,
                                                    const unsigned* __restrict__ srcs,
                                                    const float* __restrict__ g,
                                                    float* __restrict__ raw) {
    int lane = threadIdx.x & 63;
    int node = (blockIdx.x * blockDim.x + threadIdx.x) >> 6;
    if (node >= NV) return;
    int grp = lane >> 4, sub = lane & 15;
    int e0 = beg[node], en = end[node];
    float4 acc;
    if (grp == 0) {
        acc = ((const float4*)(g + ((size_t)node << 6)))[sub];  // self loop
    } else {
        acc = make_float4(0.f, 0.f, 0.f, 0.f);
    }
    int e = e0 + grp;
    for (; e + 4 < en; e += 8) {
        int s0 = srcs[e], s1 = srcs[e + 4];
        float4 v0 = ((const float4*)(g + ((size_t)s0 << 6)))[sub];
        float4 v1 = ((const float4*)(g + ((size_t)s1 << 6)))[sub];
        acc.x += v0.x + v1.x; acc.y += v0.y + v1.y;
        acc.z += v0.z + v1.z; acc.w += v0.w + v1.w;
    }
    if (e < en) {
        int s = srcs[e];
        float4 v = ((const float4*)(g + ((size_t)s << 6)))[sub];
        acc.x += v.x; acc.y += v.y; acc.z += v.z; acc.w += v.w;
    }
    acc.x += __shfl_xor(acc.x, 16); acc.y += __shfl_xor(acc.y, 16);
    acc.z += __shfl_xor(acc.z, 16); acc.w += __shfl_xor(acc.w, 16);
    acc.x += __shfl_xor(acc.x, 32); acc.y += __shfl_xor(acc.y, 32);
    acc.z += __shfl_xor(acc.z, 32); acc.w += __shfl_xor(acc.w, 32);
    if (grp == 0)
        ((float4*)(raw + ((size_t)node << 6)))[sub] = acc;
}

// ---------------------------------------------------------------------------
// Fused layer-2 transform + partial pooling, v5: 4x4 register-tiled GEMM.
// Rounds 9/11/12/13 post-mortem: every variant paying >=0.5 operand-fetch
// instrs per FMA lands at ~44 us regardless of operand home. This version:
// per k, ONE ds_read_b128 of W2[k][c0..c0+4) + ONE ds_read_b128 of the
// transposed row tile rT[k][r0..r0+4) feed SIXTEEN FMAs (0.125 fetch/FMA).
// Rows staged transposed per wave (coalesced loads -> 4 ds_write_b128,
// stride RST=20 words keeps 16B alignment). acc[4][4] fully unrolled
// (static indices). ~50 VGPR < the compiler's 64 cap -> no spill possible.
// Column partials reduced across row-groups via shfl_xor(16/32).
// ---------------------------------------------------------------------------
__global__ __launch_bounds__(256) void trans2pool_kernel(const float* __restrict__ q1,
                                                         const float* __restrict__ dinv,
                                                         const float* __restrict__ b2,
                                                         const float* __restrict__ W2,
                                                         float* __restrict__ partials) {
    __shared__ float w2s[64 * 64];        // 16 KB, [k][d]
    __shared__ float rT[4][64 * RST];     // 20 KB, per-wave transposed rows [k][r]
    int t = threadIdx.x;
    int lane = t & 63, wvid = t >> 6;
    for (int i = t; i < 64 * 64; i += 256) w2s[i] = W2[i];

    int wid = blockIdx.x * 4 + wvid;
    int n0 = wid * RPW;
    // stage: lane holds column `lane` (k = lane) of the 16x64 row tile
    float v[16];
    #pragma unroll
    for (int i = 0; i < 16; ++i) v[i] = q1[((size_t)(n0 + i) << 6) + lane];
    float* rw = rT[wvid];
    #pragma unroll
    for (int r0 = 0; r0 < 16; r0 += 4)
        *(float4*)&rw[lane * RST + r0] = make_float4(v[r0], v[r0 + 1], v[r0 + 2], v[r0 + 3]);
    __syncthreads();

    int ri0 = (lane >> 4) * 4;            // row sub-tile: 0,4,8,12
    int c0 = (lane & 15) * 4;             // col sub-tile: 0..60
    float acc00 = 0.f, acc01 = 0.f, acc02 = 0.f, acc03 = 0.f;
    float acc10 = 0.f, acc11 = 0.f, acc12 = 0.f, acc13 = 0.f;
    float acc20 = 0.f, acc21 = 0.f, acc22 = 0.f, acc23 = 0.f;
    float acc30 = 0.f, acc31 = 0.f, acc32 = 0.f, acc33 = 0.f;
    #pragma unroll 2
    for (int k = 0; k < 64; ++k) {
        float4 w4 = *(const float4*)&w2s[k * 64 + c0];
        float4 r4 = *(const float4*)&rw[k * RST + ri0];
        acc00 = fmaf(r4.x, w4.x, acc00); acc01 = fmaf(r4.x, w4.y, acc01);
        acc02 = fmaf(r4.x, w4.z, acc02); acc03 = fmaf(r4.x, w4.w, acc03);
        acc10 = fmaf(r4.y, w4.x, acc10); acc11 = fmaf(r4.y, w4.y, acc11);
        acc12 = fmaf(r4.y, w4.z, acc12); acc13 = fmaf(r4.y, w4.w, acc13);
        acc20 = fmaf(r4.z, w4.x, acc20); acc21 = fmaf(r4.z, w4.y, acc21);
        acc22 = fmaf(r4.z, w4.z, acc22); acc23 = fmaf(r4.z, w4.w, acc23);
        acc30 = fmaf(r4.w, w4.x, acc30); acc31 = fmaf(r4.w, w4.y, acc31);
        acc32 = fmaf(r4.w, w4.z, acc32); acc33 = fmaf(r4.w, w4.w, acc33);
    }
    // epilogue: relu(dinv*acc + b2), sum over this lane's 4 rows
    float4 bv = *(const float4*)&b2[c0];
    float d0 = dinv[n0 + ri0 + 0], d1 = dinv[n0 + ri0 + 1];
    float d2 = dinv[n0 + ri0 + 2], d3 = dinv[n0 + ri0 + 3];
    float s0 = fmaxf(fmaf(d0, acc00, bv.x), 0.f) + fmaxf(fmaf(d1, acc10, bv.x), 0.f)
             + fmaxf(fmaf(d2, acc20, bv.x), 0.f) + fmaxf(fmaf(d3, acc30, bv.x), 0.f);
    float s1 = fmaxf(fmaf(d0, acc01, bv.y), 0.f) + fmaxf(fmaf(d1, acc11, bv.y), 0.f)
             + fmaxf(fmaf(d2, acc21, bv.y), 0.f) + fmaxf(fmaf(d3, acc31, bv.y), 0.f);
    float s2 = fmaxf(fmaf(d0, acc02, bv.z), 0.f) + fmaxf(fmaf(d1, acc12, bv.z), 0.f)
             + fmaxf(fmaf(d2, acc22, bv.z), 0.f) + fmaxf(fmaf(d3, acc32, bv.z), 0.f);
    float s3 = fmaxf(fmaf(d0, acc03, bv.w), 0.f) + fmaxf(fmaf(d1, acc13, bv.w), 0.f)
             + fmaxf(fmaf(d2, acc23, bv.w), 0.f) + fmaxf(fmaf(d3, acc33, bv.w), 0.f);
    // reduce across the 4 row-groups (lanes l, l^16, l^32, l^48 share c0)
    s0 += __shfl_xor(s0, 16); s1 += __shfl_xor(s1, 16);
    s2 += __shfl_xor(s2, 16); s3 += __shfl_xor(s3, 16);
    s0 += __shfl_xor(s0, 32); s1 += __shfl_xor(s1, 32);
    s2 += __shfl_xor(s2, 32); s3 += __shfl_xor(s3, 32);
    if (lane < 16)
        *(float4*)&partials[(size_t)wid * 64 + c0] = make_float4(s0, s1, s2, s3);
}

// Reduce WPG=125 partials per graph; apply head.
__global__ __launch_bounds__(64) void pool_finish_kernel(const float* __restrict__ partials,
                                                         const float* __restrict__ Wh,
                                                         const float* __restrict__ bh,
                                                         float* __restrict__ out) {
    __shared__ float pooled[64];
    int b = blockIdx.x;
    int t = threadIdx.x;
    float s = 0.f;
    for (int c = 0; c < WPG; ++c)
        s += partials[((size_t)(b * WPG + c)) * 64 + t];
    pooled[t] = s * (1.0f / NN);
    __syncthreads();
    if (t < 2) {
        float o = bh[t];
        #pragma unroll 16
        for (int k = 0; k < 64; ++k) o += pooled[k] * Wh[k * 2 + t];
        out[b * 2 + t] = o;
    }
}

extern "C" void kernel_launch(void* const* d_in, const int* in_sizes, int n_in,
                              void* d_out, int out_size, void* d_ws, size_t ws_size,
                              hipStream_t stream) {
    const float* x  = (const float*)d_in[0];
    const int*   ei = (const int*)d_in[1];
    const float* W1 = (const float*)d_in[2];
    const float* b1 = (const float*)d_in[3];
    const float* W2 = (const float*)d_in[4];
    const float* b2 = (const float*)d_in[5];
    const float* Wh = (const float*)d_in[6];
    const float* bh = (const float*)d_in[7];
    float* out = (float*)d_out;

    float* ws   = (float*)d_ws;
    float* bufA = ws;                          // NV*DD  (p1)
    float* bufB = bufA + (size_t)NV * DD;      // NV*DD  (q1)
    float* p0   = bufB + (size_t)NV * DD;      // NV*FF
    float4* q04 = (float4*)(p0 + (size_t)NV * FF);  // NV
    float* dinv = (float*)(q04 + NV);          // NV
    float* partials = dinv + NV;               // NWAVES*64
    unsigned* parts = (unsigned*)(partials + (size_t)NWAVES * 64);  // KB*CAP
    int*   beg  = (int*)(parts + (size_t)KB * CAP);                 // NV
    int*   end  = beg + NV;                    // NV
    int*   gcur = end + NV;                    // KB
    int*   flag = gcur + KB;                   // 1

    // --- Build bucketed, per-bucket-sorted edge structure ---
    setup_kernel<<<4, 256, 0, stream>>>(ei, flag, gcur);
    part_kernel<<<NBLKA, 256, 0, stream>>>(ei, flag, gcur, parts);
    bsort_kernel<<<KB, 256, 0, stream>>>(parts, gcur, beg, end, dinv);

    // --- p0 = dinv * temporal-mean(x) ---
    tmean_kernel<<<(NV * FF + 255) / 256, 256, 0, stream>>>(x, dinv, p0);

    // --- Layer 1 aggregation (3-dim gather) -> q04 = {q0, dinv} ---
    agg3_kernel<<<(NV + 255) / 256, 256, 0, stream>>>(beg, end, parts, p0, dinv, q04);

    // --- Layer 1 transform (once per node) ---
    trans1_kernel<<<NV * DD / 256, 256, 0, stream>>>(q04, W1, b1, bufA);

    // --- Layer 2 aggregation (float4-per-lane, 4 edges/instr) ---
    agg64_kernel<<<NV * 64 / 256, 256, 0, stream>>>(beg, end, parts, bufA, bufB);

    // --- Fused layer-2 transform + partial pool (4x4 register-tiled GEMM) ---
    trans2pool_kernel<<<NWAVES / 4, 256, 0, stream>>>(bufB, dinv, b2, W2, partials);

    // --- Head ---
    pool_finish_kernel<<<BB, 64, 0, stream>>>(partials, Wh, bh, out);
}